// Round 3
// baseline (182.838 us; speedup 1.0000x reference)
//
#include <hip/hip_runtime.h>
#include <stdint.h>

#define NN 4096
#define FF 256
#define HH 4
#define DD 64
#define NEG 0.2f
#define LOG2E 1.4426950408889634f

#define ITILE 64
#define CJ 64

typedef __attribute__((ext_vector_type(8))) short short8;
typedef __attribute__((ext_vector_type(4))) float f32x4;
typedef __attribute__((ext_vector_type(16))) float f32x16;

__device__ __forceinline__ uint16_t bf16_rh(float f) {
    uint32_t u = __float_as_uint(f);
    return (uint16_t)((u + 0x8000u) >> 16);
}
__device__ __forceinline__ uint32_t pk2(float a, float b) {
    uint32_t ua = __float_as_uint(a) + 0x8000u;
    uint32_t ub = __float_as_uint(b) + 0x8000u;
    return (ua >> 16) | (ub & 0xffff0000u);
}
// load 8 consecutive f32, convert to 8 bf16 (round-half-up, matches cvt path)
__device__ __forceinline__ short8 ld_bf8(const float* __restrict__ p) {
    float4 v0 = *(const float4*)p;
    float4 v1 = *(const float4*)(p + 4);
    union { uint32_t u[4]; short8 v; } o;
    o.u[0] = pk2(v0.x, v0.y); o.u[1] = pk2(v0.z, v0.w);
    o.u[2] = pk2(v1.x, v1.y); o.u[3] = pk2(v1.z, v1.w);
    return o.v;
}

// ---------------- h = x @ W^T (bf16 MFMA, on-the-fly f32->bf16 conversion) --
// + FUSED s,t dots (log2-scaled) + bf16 transposed H_T + pden zeroing.
// grid (NN/64, HH): blockIdx.y is exactly one head (64 f = one D-range).
__global__ __launch_bounds__(256) void gemm_h(const float* __restrict__ x,
                                              const float* __restrict__ W,
                                              const float* __restrict__ a_src,
                                              const float* __restrict__ a_dst,
                                              float* __restrict__ s,
                                              float* __restrict__ T_T,
                                              uint16_t* __restrict__ H_T,
                                              float* __restrict__ pden) {
    const int tid = threadIdx.x;
    if (blockIdx.y == 0) pden[blockIdx.x * 256 + tid] = 0.f;  // 64 blk * 256 = NN*HH
    const int w = tid >> 6, l = tid & 63;
    const int m = l & 15, q = l >> 4;             // 16x16x32: m=l&15, k=q*8+j
    const int i0 = blockIdx.x * 64 + w * 16;
    const int f0 = blockIdx.y * 64;
    const int hh = blockIdx.y;                    // head index
    f32x4 acc[4];
#pragma unroll
    for (int n = 0; n < 4; n++)
#pragma unroll
        for (int r = 0; r < 4; r++) acc[n][r] = 0.f;
    const float* arow = x + (size_t)(i0 + m) * FF + q * 8;
#pragma unroll
    for (int k0 = 0; k0 < FF; k0 += 32) {
        short8 af = ld_bf8(arow + k0);
#pragma unroll
        for (int n = 0; n < 4; n++) {
            short8 bf = ld_bf8(W + (size_t)(f0 + n * 16 + m) * FF + k0 + q * 8);
            acc[n] = __builtin_amdgcn_mfma_f32_16x16x32_bf16(af, bf, acc[n], 0, 0, 0);
        }
    }
    // ---- fused epilogue: s,t dots (log2-scaled) ----
    const float* as = a_src + hh * DD;
    const float* ad = a_dst + hh * DD;
    float av[4], dv[4];
#pragma unroll
    for (int n = 0; n < 4; n++) { av[n] = as[n * 16 + m]; dv[n] = ad[n * 16 + m]; }
#pragma unroll
    for (int r = 0; r < 4; r++) {
        float vs = 0.f, vd = 0.f;
#pragma unroll
        for (int n = 0; n < 4; n++) {
            vs = fmaf(acc[n][r], av[n], vs);
            vd = fmaf(acc[n][r], dv[n], vd);
        }
#pragma unroll
        for (int off = 1; off < 16; off <<= 1) {  // reduce across m
            vs += __shfl_xor(vs, off, 64);
            vd += __shfl_xor(vd, off, 64);
        }
        if (m == 0) {
            const int i = i0 + q * 4 + r;         // C: col=l&15 -> f, row=q*4+r -> i
            s[(size_t)i * HH + hh] = vs * LOG2E;  // log2-domain scores
            T_T[(size_t)hh * NN + i] = vd * LOG2E;
        }
    }
    // ---- fused epilogue: bf16 transposed H_T[f][i] ----
#pragma unroll
    for (int n = 0; n < 4; n++) {
        ushort4 o;
        o.x = bf16_rh(acc[n][0]); o.y = bf16_rh(acc[n][1]);
        o.z = bf16_rh(acc[n][2]); o.w = bf16_rh(acc[n][3]);
        *(ushort4*)(H_T + (size_t)(f0 + n * 16 + m) * NN + i0 + q * 4) = o;
    }
}

// ---------------- fused scores -> exp2 -> P -> MFMA PV ----------------------
// block: 64 i x (NN/NS) j-slice; wave w = head w. TWO i-halves (m, m+32) per
// lane share the t / H_T / adj-stage loads -> 2x compute per L2 byte (ILP
// over TLP; occupancy was resource-bound at ~35%). adj double-buffered in
// LDS: ONE barrier per 64-j chunk. Scores in log2-domain, exp2 direct.
template<int NS>
__global__ __launch_bounds__(256, 3) void gat_main(
    const float* __restrict__ adj, const uint16_t* __restrict__ H_T,
    const float* __restrict__ s, const float* __restrict__ T_T,
    float* __restrict__ pden, uint16_t* __restrict__ part) {
    constexpr int JR = NN / NS;
    constexpr int NCH = JR / CJ;
    __shared__ float adj_s[2][CJ][ITILE + 1];     // 2 x 64 x 65 x 4B = 33.3 KB
    const int tid = threadIdx.x;
    const int w = tid >> 6, l = tid & 63;
    const int m = l & 31, q = l >> 5;             // 32x32x16: m=l&31, k=q*8+j
    // bijective XCD swizzle (nwg % 8 == 0): same-XCD blocks share a j-slice
    constexpr int NWG = (NN / ITILE) * NS;
    const int orig = blockIdx.y * (NN / ITILE) + blockIdx.x;
    const int swz = (orig & 7) * (NWG / 8) + (orig >> 3);
    const int i0 = (swz & (NN / ITILE - 1)) * ITILE;
    const int sl = swz / (NN / ITILE);
    const int jb = sl * JR;

    const float sA = s[(size_t)(i0 + m) * HH + w];       // *log2e already
    const float sB = s[(size_t)(i0 + 32 + m) * HH + w];
    const float cA = NEG * sA, cB = NEG * sB;
    float denA = 0.f, denB = 0.f;
    f32x16 acc0a, acc1a, acc0b, acc1b;            // 64 AGPR
#pragma unroll
    for (int r = 0; r < 16; r++) {
        acc0a[r] = 0.f; acc1a[r] = 0.f; acc0b[r] = 0.f; acc1b[r] = 0.f;
    }
    const float* trow = T_T + (size_t)w * NN;
    const uint16_t* b0row = H_T + (size_t)(w * DD + m) * NN;
    const uint16_t* b1row = H_T + (size_t)(w * DD + 32 + m) * NN;

    // staging geometry: thread stages adj[i0+is][jc+j16 .. +15] (4 float4)
    const int is = tid >> 2, j16 = (tid & 3) * 16;
    const float* arow = adj + (size_t)(i0 + is) * NN + j16;

    float4 pre[4];
#pragma unroll
    for (int c4 = 0; c4 < 4; c4++) pre[c4] = *(const float4*)(arow + jb + c4 * 4);
#pragma unroll
    for (int c4 = 0; c4 < 4; c4++) {
        adj_s[0][j16 + c4 * 4 + 0][is] = pre[c4].x;
        adj_s[0][j16 + c4 * 4 + 1][is] = pre[c4].y;
        adj_s[0][j16 + c4 * 4 + 2][is] = pre[c4].z;
        adj_s[0][j16 + c4 * 4 + 3][is] = pre[c4].w;
    }
#pragma unroll
    for (int c4 = 0; c4 < 4; c4++) pre[c4] = *(const float4*)(arow + jb + CJ + c4 * 4);
    __syncthreads();

    for (int c = 0; c < NCH; ++c) {
        const int jc = jb + c * CJ;
        const int cur = c & 1;
        if (c + 1 < NCH) {                        // ds_write next chunk (other buf)
#pragma unroll
            for (int c4 = 0; c4 < 4; c4++) {
                adj_s[cur ^ 1][j16 + c4 * 4 + 0][is] = pre[c4].x;
                adj_s[cur ^ 1][j16 + c4 * 4 + 1][is] = pre[c4].y;
                adj_s[cur ^ 1][j16 + c4 * 4 + 2][is] = pre[c4].z;
                adj_s[cur ^ 1][j16 + c4 * 4 + 3][is] = pre[c4].w;
            }
            if (c + 2 < NCH) {                    // prefetch chunk c+2 -> regs
#pragma unroll
                for (int c4 = 0; c4 < 4; c4++)
                    pre[c4] = *(const float4*)(arow + jc + 2 * CJ + c4 * 4);
            }
        }
#pragma unroll
        for (int kk = 0; kk < CJ; kk += 16) {
            const int jg = jc + kk + q * 8;       // this lane's first j (global)
            float4 t0 = *(const float4*)(trow + jg);
            float4 t1 = *(const float4*)(trow + jg + 4);
            float tt[8] = {t0.x, t0.y, t0.z, t0.w, t1.x, t1.y, t1.z, t1.w};
            uint32_t pka[4], pkb[4];
#pragma unroll
            for (int jj = 0; jj < 8; jj += 2) {
                const int rr = kk + q * 8 + jj;
                float a0A = adj_s[cur][rr][m],      a1A = adj_s[cur][rr + 1][m];
                float a0B = adj_s[cur][rr][m + 32], a1B = adj_s[cur][rr + 1][m + 32];
                float tv0 = tt[jj], tv1 = tt[jj + 1];
                float y0 = NEG * tv0, y1 = NEG * tv1;   // shared between halves
                // half A (rows i0+m)
                float xa0 = sA + tv0, xa1 = sA + tv1;
                float la0 = fmaxf(xa0, y0 + cA), la1 = fmaxf(xa1, y1 + cA);
                float ea0, ea1;
                asm("v_exp_f32 %0, %1" : "=v"(ea0) : "v"(la0));
                asm("v_exp_f32 %0, %1" : "=v"(ea1) : "v"(la1));
                ea0 = (a0A > 0.f) ? ea0 : 0.f;
                ea1 = (a1A > 0.f) ? ea1 : 0.f;
                denA += ea0 + ea1;
                pka[jj >> 1] = pk2(ea0 * a0A, ea1 * a1A);
                // half B (rows i0+32+m)
                float xb0 = sB + tv0, xb1 = sB + tv1;
                float lb0 = fmaxf(xb0, y0 + cB), lb1 = fmaxf(xb1, y1 + cB);
                float eb0, eb1;
                asm("v_exp_f32 %0, %1" : "=v"(eb0) : "v"(lb0));
                asm("v_exp_f32 %0, %1" : "=v"(eb1) : "v"(lb1));
                eb0 = (a0B > 0.f) ? eb0 : 0.f;
                eb1 = (a1B > 0.f) ? eb1 : 0.f;
                denB += eb0 + eb1;
                pkb[jj >> 1] = pk2(eb0 * a0B, eb1 * a1B);
            }
            union { uint32_t u[4]; short8 v; } ua, ub;
#pragma unroll
            for (int c4 = 0; c4 < 4; c4++) { ua.u[c4] = pka[c4]; ub.u[c4] = pkb[c4]; }
            short8 bf0 = *(const short8*)(b0row + jg);
            short8 bf1 = *(const short8*)(b1row + jg);
            acc0a = __builtin_amdgcn_mfma_f32_32x32x16_bf16(ua.v, bf0, acc0a, 0, 0, 0);
            acc1a = __builtin_amdgcn_mfma_f32_32x32x16_bf16(ua.v, bf1, acc1a, 0, 0, 0);
            acc0b = __builtin_amdgcn_mfma_f32_32x32x16_bf16(ub.v, bf0, acc0b, 0, 0, 0);
            acc1b = __builtin_amdgcn_mfma_f32_32x32x16_bf16(ub.v, bf1, acc1b, 0, 0, 0);
        }
        __syncthreads();
    }
    denA += __shfl_down(denA, 32, 64);            // lanes l, l+32 share m
    denB += __shfl_down(denB, 32, 64);
    if (l < 32) {
        atomicAdd(&pden[(size_t)(i0 + m) * HH + w], denA);
        atomicAdd(&pden[(size_t)(i0 + 32 + m) * HH + w], denB);
    }
    uint16_t* pbase = part + (size_t)sl * NN * FF;
#pragma unroll
    for (int reg = 0; reg < 16; reg++) {
        int row = (reg & 3) + 8 * (reg >> 2) + 4 * q;  // C: col=l&31, verified m74
        pbase[(size_t)(i0 + row) * FF + w * DD + m]           = bf16_rh(acc0a[reg]);
        pbase[(size_t)(i0 + row) * FF + w * DD + 32 + m]      = bf16_rh(acc1a[reg]);
        pbase[(size_t)(i0 + 32 + row) * FF + w * DD + m]      = bf16_rh(acc0b[reg]);
        pbase[(size_t)(i0 + 32 + row) * FF + w * DD + 32 + m] = bf16_rh(acc1b[reg]);
    }
}

// ---------------- sum slice partials, divide by denom (vectorized) ----------
// block: 4 i-rows x 64 lanes; thread handles 4 consecutive f via ushort4.
template<int NS>
__global__ __launch_bounds__(256) void finalize(const uint16_t* __restrict__ part,
                                                const float* __restrict__ pden,
                                                float* __restrict__ out) {
    const int i = blockIdx.x * 4 + (threadIdx.x >> 6);
    const int fq = (threadIdx.x & 63) * 4;
    float s0 = 0.f, s1 = 0.f, s2 = 0.f, s3 = 0.f;
#pragma unroll
    for (int sl = 0; sl < NS; sl++) {
        ushort4 v = *(const ushort4*)(part + (size_t)sl * NN * FF + (size_t)i * FF + fq);
        s0 += __uint_as_float(((uint32_t)v.x) << 16);
        s1 += __uint_as_float(((uint32_t)v.y) << 16);
        s2 += __uint_as_float(((uint32_t)v.z) << 16);
        s3 += __uint_as_float(((uint32_t)v.w) << 16);
    }
    float d = pden[(size_t)i * HH + (fq >> 6)];
    float inv = (d > 0.f) ? 1.f / d : 0.f;
    *(float4*)(out + (size_t)i * FF + fq) =
        make_float4(s0 * inv, s1 * inv, s2 * inv, s3 * inv);
}

extern "C" void kernel_launch(void* const* d_in, const int* in_sizes, int n_in,
                              void* d_out, int out_size, void* d_ws, size_t ws_size,
                              hipStream_t stream) {
    const float* x     = (const float*)d_in[0];
    const float* adj   = (const float*)d_in[1];
    const float* W     = (const float*)d_in[2];
    const float* a_src = (const float*)d_in[3];
    const float* a_dst = (const float*)d_in[4];
    float* out = (float*)d_out;

    char* ws = (char*)d_ws;
    uint16_t* H_T  = (uint16_t*)ws;                                // 2 MB
    float*    s    = (float*)(ws + (2u << 20));                    // 64 KB
    float*    T_T  = s + (size_t)NN * HH;                          // 64 KB
    float*    pden = T_T + (size_t)HH * NN;                        // 64 KB
    uint16_t* part = (uint16_t*)(ws + (3u << 20));                 // NS * 2 MB

    gemm_h<<<dim3(NN / 64, HH), 256, 0, stream>>>(x, W, a_src, a_dst, s, T_T, H_T, pden);
    if (ws_size >= (3u << 20) + (size_t)16 * NN * FF * sizeof(uint16_t)) {
        gat_main<16><<<dim3(NN / ITILE, 16), 256, 0, stream>>>(adj, H_T, s, T_T, pden, part);
        finalize<16><<<NN / 4, 256, 0, stream>>>(part, pden, out);
    } else {
        gat_main<8><<<dim3(NN / ITILE, 8), 256, 0, stream>>>(adj, H_T, s, T_T, pden, part);
        finalize<8><<<NN / 4, 256, 0, stream>>>(part, pden, out);
    }
}